// Round 1
// baseline (142.706 us; speedup 1.0000x reference)
//
#include <hip/hip_runtime.h>
#include <hip/hip_bf16.h>
#include <math.h>

// Problem dims (fixed by reference)
#define VV 50257
#define II 1024
#define HH 1024
#define LL 16384
#define EPSF 1e-8f

// ---------------- prep: cat1 = [emb_row | h0], cat2[0:I] = emb_row ----------
__global__ void prep_kernel(const int* __restrict__ token,
                            const float* __restrict__ emb,
                            const float* __restrict__ hidden,
                            float* __restrict__ cat1, float* __restrict__ cat2) {
    int t = token[0];
    const float* er = emb + (size_t)t * II;
    for (int i = threadIdx.x + blockIdx.x * blockDim.x; i < II;
         i += gridDim.x * blockDim.x) {
        float e = er[i];
        cat1[i] = e;
        cat2[i] = e;
        cat1[II + i] = hidden[i];
    }
}

// ---------------- generic matvec: y[r] = act(b[r] + dot(W[r,:], x)) ---------
// one wave (64 lanes) per row, float4 loads; K % 256 == 0
template <int ACT>  // 0 = none, 1 = relu
__global__ void matvec_kernel(const float* __restrict__ W,
                              const float* __restrict__ x,
                              const float* __restrict__ b,
                              float* __restrict__ y, int R, int K) {
    int wave = (blockIdx.x * blockDim.x + threadIdx.x) >> 6;
    int lane = threadIdx.x & 63;
    if (wave >= R) return;
    const float* row = W + (size_t)wave * K;
    float acc = 0.f;
    for (int k = lane * 4; k < K; k += 256) {
        float4 wv = *reinterpret_cast<const float4*>(row + k);
        float4 xv = *reinterpret_cast<const float4*>(x + k);
        acc += wv.x * xv.x + wv.y * xv.y + wv.z * xv.z + wv.w * xv.w;
    }
    #pragma unroll
    for (int off = 32; off; off >>= 1) acc += __shfl_down(acc, off);
    if (lane == 0) {
        float v = acc + b[wave];
        if (ACT) v = fmaxf(v, 0.f);
        y[wave] = v;
    }
}

// ---------------- qn = max(||q||, eps), single block ------------------------
__global__ void norm_kernel(const float* __restrict__ v, float* __restrict__ out,
                            int n) {
    float ss = 0.f;
    for (int i = threadIdx.x; i < n; i += blockDim.x) {
        float t = v[i];
        ss += t * t;
    }
    #pragma unroll
    for (int off = 32; off; off >>= 1) ss += __shfl_down(ss, off);
    __shared__ float red[16];
    int wave = threadIdx.x >> 6, lane = threadIdx.x & 63;
    if (lane == 0) red[wave] = ss;
    __syncthreads();
    if (threadIdx.x == 0) {
        float s = 0.f;
        int nw = blockDim.x >> 6;
        for (int i = 0; i < nw; ++i) s += red[i];
        out[0] = fmaxf(sqrtf(s), EPSF);
    }
}

// ---------------- sims[l] = dot(enc[l], q) / (qn * max(||enc[l]||, eps)) ----
__global__ void sims_kernel(const float* __restrict__ enc,
                            const float* __restrict__ q,
                            const float* __restrict__ qn_ptr,
                            float* __restrict__ sims) {
    int wave = (blockIdx.x * blockDim.x + threadIdx.x) >> 6;
    int lane = threadIdx.x & 63;
    if (wave >= LL) return;
    const float* row = enc + (size_t)wave * HH;
    float dot = 0.f, ss = 0.f;
    for (int k = lane * 4; k < HH; k += 256) {
        float4 e = *reinterpret_cast<const float4*>(row + k);
        float4 qv = *reinterpret_cast<const float4*>(q + k);
        dot += e.x * qv.x + e.y * qv.y + e.z * qv.z + e.w * qv.w;
        ss += e.x * e.x + e.y * e.y + e.z * e.z + e.w * e.w;
    }
    #pragma unroll
    for (int off = 32; off; off >>= 1) {
        dot += __shfl_down(dot, off);
        ss += __shfl_down(ss, off);
    }
    if (lane == 0) {
        float en = fmaxf(sqrtf(ss), EPSF);
        sims[wave] = dot / (qn_ptr[0] * en);
    }
}

// ---------------- softmax over 16384 -> attn_weights (normalized) ----------
__global__ void softmax_kernel(const float* __restrict__ sims,
                               float* __restrict__ w_out, int n) {
    __shared__ float red[16];
    __shared__ float s_max, s_sum;
    int wave = threadIdx.x >> 6, lane = threadIdx.x & 63;
    // pass 1: max
    float m = -INFINITY;
    for (int i = threadIdx.x; i < n; i += blockDim.x) m = fmaxf(m, sims[i]);
    #pragma unroll
    for (int off = 32; off; off >>= 1) m = fmaxf(m, __shfl_down(m, off));
    if (lane == 0) red[wave] = m;
    __syncthreads();
    if (threadIdx.x == 0) {
        float t = -INFINITY;
        for (int i = 0; i < (int)(blockDim.x >> 6); ++i) t = fmaxf(t, red[i]);
        s_max = t;
    }
    __syncthreads();
    float lm = s_max;
    // pass 2: sum of exp
    float s = 0.f;
    for (int i = threadIdx.x; i < n; i += blockDim.x) s += expf(sims[i] - lm);
    #pragma unroll
    for (int off = 32; off; off >>= 1) s += __shfl_down(s, off);
    __syncthreads();
    if (lane == 0) red[wave] = s;
    __syncthreads();
    if (threadIdx.x == 0) {
        float t = 0.f;
        for (int i = 0; i < (int)(blockDim.x >> 6); ++i) t += red[i];
        s_sum = t;
    }
    __syncthreads();
    float inv = 1.f / s_sum;
    // pass 3: write normalized weights
    for (int i = threadIdx.x; i < n; i += blockDim.x)
        w_out[i] = expf(sims[i] - lm) * inv;
}

// ---------------- partial column sums: attn_applied pieces ------------------
// grid = (HH/256, nRowChunks), block = 256
__global__ void colsum_kernel(const float* __restrict__ enc,
                              const float* __restrict__ w,
                              float* __restrict__ partial, int rowsPerChunk) {
    int c = blockIdx.x * 256 + threadIdx.x;
    int r0 = blockIdx.y * rowsPerChunk;
    float acc = 0.f;
    for (int r = r0; r < r0 + rowsPerChunk; ++r)
        acc = fmaf(w[r], enc[(size_t)r * HH + c], acc);
    partial[(size_t)blockIdx.y * HH + c] = acc;
}

// ---------------- reduce partials -> cat2[II + c] ---------------------------
__global__ void reduce_partials_kernel(const float* __restrict__ partial,
                                       float* __restrict__ out, int nChunks) {
    int c = blockIdx.x * blockDim.x + threadIdx.x;
    if (c >= HH) return;
    float acc = 0.f;
    for (int i = 0; i < nChunks; ++i) acc += partial[(size_t)i * HH + c];
    out[c] = acc;
}

// ---------------- GRU gate fusion: h_new -> d_out[1..1024] ------------------
__global__ void gru_kernel(const float* __restrict__ gi,
                           const float* __restrict__ gh,
                           const float* __restrict__ h0,
                           float* __restrict__ h_new) {
    int i = blockIdx.x * blockDim.x + threadIdx.x;
    if (i >= HH) return;
    float r = 1.f / (1.f + expf(-(gi[i] + gh[i])));
    float z = 1.f / (1.f + expf(-(gi[HH + i] + gh[HH + i])));
    float nn = tanhf(gi[2 * HH + i] + r * gh[2 * HH + i]);
    h_new[i] = (1.f - z) * nn + z * h0[i];
}

// ---------------- head: out = relu(h @ fc2^T + b) @ out_w^T + out_b ---------
__global__ void head_kernel(const float* __restrict__ h,
                            const float* __restrict__ fc2_w,
                            const float* __restrict__ fc2_b,
                            const float* __restrict__ out_w,
                            const float* __restrict__ out_b,
                            float* __restrict__ out) {
    __shared__ float f[64];
    int wave = threadIdx.x >> 6, lane = threadIdx.x & 63;  // 16 waves
    for (int rr = 0; rr < 4; ++rr) {
        int r = wave * 4 + rr;
        const float* row = fc2_w + (size_t)r * HH;
        float acc = 0.f;
        for (int k = lane * 4; k < HH; k += 256) {
            float4 wv = *reinterpret_cast<const float4*>(row + k);
            float4 hv = *reinterpret_cast<const float4*>(h + k);
            acc += wv.x * hv.x + wv.y * hv.y + wv.z * hv.z + wv.w * hv.w;
        }
        #pragma unroll
        for (int off = 32; off; off >>= 1) acc += __shfl_down(acc, off);
        if (lane == 0) f[r] = fmaxf(acc + fc2_b[r], 0.f);
    }
    __syncthreads();
    if (threadIdx.x < 64) {
        float v = f[threadIdx.x] * out_w[threadIdx.x];
        #pragma unroll
        for (int off = 32; off; off >>= 1) v += __shfl_down(v, off);
        if (threadIdx.x == 0) out[0] = v + out_b[0];
    }
}

extern "C" void kernel_launch(void* const* d_in, const int* in_sizes, int n_in,
                              void* d_out, int out_size, void* d_ws,
                              size_t ws_size, hipStream_t stream) {
    const int*   token = (const int*)d_in[0];
    const float* hidden = (const float*)d_in[1];
    const float* enc = (const float*)d_in[2];
    const float* emb = (const float*)d_in[3];
    const float* attn_w = (const float*)d_in[4];
    const float* attn_b = (const float*)d_in[5];
    const float* comb_w = (const float*)d_in[6];
    const float* comb_b = (const float*)d_in[7];
    const float* w_ih = (const float*)d_in[8];
    const float* w_hh = (const float*)d_in[9];
    const float* b_ih = (const float*)d_in[10];
    const float* b_hh = (const float*)d_in[11];
    const float* fc2_w = (const float*)d_in[12];
    const float* fc2_b = (const float*)d_in[13];
    const float* out_w = (const float*)d_in[14];
    const float* out_b = (const float*)d_in[15];

    float* ws = (float*)d_ws;
    // ws layout (floats)
    float* cat1 = ws + 0;        // 2048
    float* cat2 = ws + 2048;     // 2048 (second half = attn_applied)
    float* q    = ws + 4096;     // 1024
    float* qn   = ws + 5120;     // 1
    float* x    = ws + 6144;     // 1024
    float* gi   = ws + 7168;     // 3072
    float* gh   = ws + 10240;    // 3072
    float* sims = ws + 16384;    // 16384
    float* part = ws + 32768;    // nRowChunks * 1024

    // pick row-chunk count that fits ws
    int nRowChunks = 256;
    while (nRowChunks > 8 &&
           (size_t)(32768 + nRowChunks * 1024) * 4 > ws_size)
        nRowChunks >>= 1;
    int rowsPerChunk = LL / nRowChunks;

    float* out_scalar = (float*)d_out;           // [0]
    float* h_new = (float*)d_out + 1;            // [1..1024]
    float* attn_weights = (float*)d_out + 1 + HH; // [1025..17408]

    // 1. gather embedding row + concat with h0
    prep_kernel<<<4, 256, 0, stream>>>(token, emb, hidden, cat1, cat2);
    // 2. q = attn_w @ cat1 + attn_b       (1024 x 2048)
    matvec_kernel<0><<<256, 256, 0, stream>>>(attn_w, cat1, attn_b, q, HH,
                                              II + HH);
    // 3. qn = max(||q||, eps)
    norm_kernel<<<1, 256, 0, stream>>>(q, qn, HH);
    // 4. sims over 16384 rows             (reads enc: 64 MB)
    sims_kernel<<<4096, 256, 0, stream>>>(enc, q, qn, sims);
    // 5. softmax -> attn_weights (normalized, written to d_out)
    softmax_kernel<<<1, 1024, 0, stream>>>(sims, attn_weights, LL);
    // 6. weighted column sums             (reads enc: 64 MB)
    dim3 cs_grid(HH / 256, nRowChunks);
    colsum_kernel<<<cs_grid, 256, 0, stream>>>(enc, attn_weights, part,
                                               rowsPerChunk);
    // 7. reduce partials -> cat2[1024:2048] = attn_applied
    reduce_partials_kernel<<<4, 256, 0, stream>>>(part, cat2 + II, nRowChunks);
    // 8. x = relu(comb_w @ cat2 + comb_b) (1024 x 2048)
    matvec_kernel<1><<<256, 256, 0, stream>>>(comb_w, cat2, comb_b, x, II,
                                              II + HH);
    // 9. gi = w_ih @ x + b_ih             (3072 x 1024)
    matvec_kernel<0><<<768, 256, 0, stream>>>(w_ih, x, b_ih, gi, 3 * HH, II);
    // 10. gh = w_hh @ h0 + b_hh           (3072 x 1024)
    matvec_kernel<0><<<768, 256, 0, stream>>>(w_hh, hidden, b_hh, gh, 3 * HH,
                                              HH);
    // 11. GRU gates -> h_new (d_out[1..1024])
    gru_kernel<<<4, 256, 0, stream>>>(gi, gh, hidden, h_new);
    // 12. head -> out scalar (d_out[0])
    head_kernel<<<1, 1024, 0, stream>>>(h_new, fc2_w, fc2_b, out_w, out_b,
                                        out_scalar);
}